// Round 1
// 568.744 us; speedup vs baseline: 1.0720x; 1.0720x over previous
//
#include <hip/hip_runtime.h>
#include <math.h>

#define HIDDEN 1024
#define SEQ    4096
#define BATCH  4

typedef _Float16 f16x8 __attribute__((ext_vector_type(8)));
typedef float    floatx4 __attribute__((ext_vector_type(4)));

// async 16B global->LDS copy (m97: width=16 emits global_load_lds_dwordx4)
__device__ inline void gld16(const void* g, void* l) {
    __builtin_amdgcn_global_load_lds(
        (const __attribute__((address_space(1))) unsigned int*)g,
        (__attribute__((address_space(3))) unsigned int*)l, 16, 0, 0);
}

// ===========================================================================
// 128x128-tile kernel, 256 thr = 4 waves (2x2), wave tile 64x64.
// MODE 5: fused QKV projection. grid (24,128,1). A=Xh [16384,1024].
//         which = col0>>10 picks Wq/Wk/Wv; which<2 -> Qo/Ko[r*1024+cl];
//         which==2 -> Vt[(b*1024+cl)*4096+s].
// ===========================================================================
template<int MODE>
__global__ __launch_bounds__(256)
void gemm128_kernel(const _Float16* __restrict__ A,
                    const _Float16* __restrict__ Bq,
                    const _Float16* __restrict__ Bk,
                    const _Float16* __restrict__ Bv,
                    const float* __restrict__ bq,
                    const float* __restrict__ bk,
                    const float* __restrict__ bv,
                    float alpha,
                    _Float16* __restrict__ Eo,
                    _Float16* __restrict__ Qo,
                    _Float16* __restrict__ Ko,
                    _Float16* __restrict__ Vo,
                    float* __restrict__ Lsum,
                    int K, int lda, int ldb) {
    __shared__ __align__(16) char smem[16384];
    char* sA = smem;          // 8 KB: 128 rows x 32 f16, swizzled 16B chunks
    char* sB = smem + 8192;

    const int tid  = threadIdx.x;
    const int lane = tid & 63;
    const int w    = tid >> 6;
    const int wm   = w & 1;
    const int wn   = w >> 1;
    const int quad = lane >> 4;
    const int l16  = lane & 15;
    const int swz  = (l16 >> 1) & 3;

    int row0, col0;
    if (MODE == 5) {
        // XCD swizzle: n%8 = XCD (round-robin dispatch assumption).
        const int n    = blockIdx.x + 24 * blockIdx.y;
        const int xcd  = n & 7;
        const int slot = n >> 3;                 // 0..383
        const int cc   = slot % 24;
        const int rg   = xcd + 8 * (slot / 24);  // 0..127
        row0 = rg * 128;
        col0 = cc * 128;
    } else {
        row0 = blockIdx.y * 128;
        col0 = blockIdx.x * 128;
    }
    const int bz = blockIdx.z;

    if (MODE == 3) {
        A    += (size_t)bz * SEQ * HIDDEN;
        Bq   += (size_t)bz * SEQ * HIDDEN;
        Eo   += (size_t)bz * SEQ * SEQ;
        Lsum += (size_t)bz * SEQ;
    }

    const _Float16* Bsrc = Bq;
    int colbase = col0;
    int which = 0;
    if (MODE == 5) {
        which = col0 >> 10;
        Bsrc = (which == 0) ? Bq : (which == 1) ? Bk : Bv;
        colbase = col0 & 1023;
    }

    floatx4 acc[4][4];
    #pragma unroll
    for (int i = 0; i < 4; ++i)
        #pragma unroll
        for (int j = 0; j < 4; ++j) acc[i][j] = (floatx4){0.f, 0.f, 0.f, 0.f};

    const f16x8* pA = (const f16x8*)sA;
    const f16x8* pB = (const f16x8*)sB;

    int srow[2], scol[2];
    #pragma unroll
    for (int it = 0; it < 2; ++it) {
        const int n = tid + it * 256;
        srow[it] = n >> 2;
        scol[it] = (n & 3) ^ ((srow[it] >> 1) & 3);
    }

    for (int k0 = 0; k0 < K; k0 += 32) {
        #pragma unroll
        for (int it = 0; it < 2; ++it) {
            const int n = tid + it * 256;
            const size_t ga = (size_t)(row0 + srow[it]) * lda + (size_t)k0 + scol[it] * 8;
            const size_t gb = (size_t)(colbase + srow[it]) * ldb + (size_t)k0 + scol[it] * 8;
            gld16(A + ga, sA + n * 16);
            gld16(Bsrc + gb, sB + n * 16);
        }
        __syncthreads();

        f16x8 af[4];
        #pragma unroll
        for (int i = 0; i < 4; ++i) {
            const int r = wm * 64 + i * 16 + l16;
            af[i] = pA[r * 4 + (quad ^ swz)];
        }
        #pragma unroll
        for (int j = 0; j < 4; ++j) {
            const int c = wn * 64 + j * 16 + l16;
            const f16x8 bf = pB[c * 4 + (quad ^ swz)];
            #pragma unroll
            for (int i = 0; i < 4; ++i)
                acc[i][j] = __builtin_amdgcn_mfma_f32_16x16x32_f16(af[i], bf, acc[i][j], 0, 0, 0);
        }
        __syncthreads();
    }

    // ---- epilogue (C/D layout: col=lane&15, row=quad*4+reg) ----
    #pragma unroll
    for (int i = 0; i < 4; ++i) {
        const int r0 = row0 + wm * 64 + i * 16 + quad * 4;
        float rp[4] = {0.f, 0.f, 0.f, 0.f};

        #pragma unroll
        for (int j = 0; j < 4; ++j) {
            const int cl = (MODE == 5 ? colbase : col0) + wn * 64 + j * 16 + l16;

            if (MODE == 5) {
                const float bcol = (which == 0 ? bq : which == 1 ? bk : bv)[cl];
                if (which < 2) {
                    _Float16* O = (which == 0) ? Qo : Ko;
                    #pragma unroll
                    for (int reg = 0; reg < 4; ++reg)
                        O[(size_t)(r0 + reg) * HIDDEN + cl] =
                            (_Float16)(acc[i][j][reg] + bcol);
                } else {
                    const int bb = r0 >> 12;
                    const int s  = r0 & 4095;
                    _Float16 t[4];
                    #pragma unroll
                    for (int reg = 0; reg < 4; ++reg)
                        t[reg] = (_Float16)(acc[i][j][reg] + bcol);
                    *(uint2*)&Vo[((size_t)bb * HIDDEN + cl) * SEQ + s] = *(const uint2*)t;
                }
            } else {  // MODE 3: alpha includes log2e; exp2f -> v_exp_f32
                #pragma unroll
                for (int reg = 0; reg < 4; ++reg) {
                    const float v = exp2f(alpha * acc[i][j][reg] - 5.770780163555856f);
                    const _Float16 vh = (_Float16)v;
                    Eo[(size_t)(r0 + reg) * SEQ + cl] = vh;
                    rp[reg] += (float)vh;
                }
            }
        }

        if (MODE == 3) {
            #pragma unroll
            for (int off = 1; off < 16; off <<= 1)
                #pragma unroll
                for (int reg = 0; reg < 4; ++reg)
                    rp[reg] += __shfl_xor(rp[reg], off, 64);
            if (l16 == 0)
                #pragma unroll
                for (int reg = 0; reg < 4; ++reg)
                    atomicAdd(&Lsum[r0 + reg], rp[reg]);
        }
    }
}

// ===========================================================================
// QK^T 8-phase kernel: 256x256 tile, BK=64, 512 thr = 8 waves (2M x 4N),
// wave tile 128x64. LDS 128 KB = {A,B} x {2 dbuf} x {2 K-halves} x [256][32]f16.
// Each K-half is a [256 rows][4 x 16B-chunk] tile with the proven
// chunk ^= ((row>>1)&3) swizzle (conflict-free ds_read_b128, same geometry
// as the 128^2 kernel's 0-conflict tiles).
//
// Per K-tile t: 4 phases (rh,kh) = (0,0),(1,0),(0,1),(1,1); each phase:
//   8 x ds_read_b128 -> stage one K-half (2 x global_load_lds_dwordx4)
//   -> s_barrier -> lgkmcnt(0) -> setprio(1) -> 16 MFMA -> setprio(0) -> barrier
// Stage schedule: p0: A-kh1(t+1), p1: B-kh1(t+1), p2: A-kh0(t+2), p3: B-kh0(t+2).
// Boundary (once per K-tile): s_waitcnt vmcnt(4) -- all 4 halves of tile t
// landed, newest 2 halves (A0/B0 of t+1) stay in flight. Never drains to 0
// except the peeled last tile (T3+T4). T5 setprio around MFMA clusters.
// ===========================================================================
__global__ __launch_bounds__(512, 2)
void qk8_kernel(const _Float16* __restrict__ Q,
                const _Float16* __restrict__ Kmat,
                _Float16* __restrict__ E,
                float* __restrict__ Lsum,
                float alpha) {
    __shared__ __align__(16) char smem[131072];
    char* sA = smem;            // 64 KB: [buf*2+kh]*16384
    char* sB = smem + 65536;    // 64 KB

    const int tid  = threadIdx.x;
    const int lane = tid & 63;
    const int w    = tid >> 6;   // 0..7
    const int wm   = w & 1;      // 128-row half
    const int wn   = w >> 1;     // 0..3: 64-col group
    const int quad = lane >> 4;
    const int l16  = lane & 15;
    const int swz  = (l16 >> 1) & 3;

    // XCD swizzle within batch (256 blocks, 256%8==0 -> bijective)
    const int bx   = blockIdx.x;
    const int z    = blockIdx.y;
    const int wgid = (bx & 7) * 32 + (bx >> 3);
    const int row0 = (wgid >> 4) * 256;
    const int col0 = (wgid & 15) * 256;

    const _Float16* Abase = Q    + (size_t)z * SEQ * HIDDEN + (size_t)row0 * HIDDEN;
    const _Float16* Bbase = Kmat + (size_t)z * SEQ * HIDDEN + (size_t)col0 * HIDDEN;
    E    += (size_t)z * SEQ * SEQ;
    Lsum += (size_t)z * SEQ;

    // per-thread staging chunks: a K-half = 256 rows x 4 chunks = 1024 chunks,
    // 2 wave-issues of 512 contiguous chunks (gld16 dest = uniform + lane*16)
    const int n0 = tid, n1 = tid + 512;
    const int r0s = n0 >> 2, p0s = n0 & 3;
    const int r1s = n1 >> 2, p1s = n1 & 3;
    const int off0 = r0s * HIDDEN + (p0s ^ ((r0s >> 1) & 3)) * 8;  // pre-swizzled src
    const int off1 = r1s * HIDDEN + (p1s ^ ((r1s >> 1) & 3)) * 8;

    auto stage = [&](const _Float16* base, char* lh, int kt, int kh) {
        const int kb = kt * 64 + kh * 32;
        gld16(base + off0 + kb, lh + n0 * 16);
        gld16(base + off1 + kb, lh + n1 * 16);
    };

    floatx4 acc[8][4];
    #pragma unroll
    for (int i = 0; i < 8; ++i)
        #pragma unroll
        for (int j = 0; j < 4; ++j) acc[i][j] = (floatx4){0.f, 0.f, 0.f, 0.f};

    // prologue: tile0 (all 4 halves) + tile1 (kh0 halves) -- queue order matters
    stage(Abase, sA + 0 * 16384, 0, 0);   // A0(0)
    stage(Bbase, sB + 0 * 16384, 0, 0);   // B0(0)
    stage(Abase, sA + 1 * 16384, 0, 1);   // A1(0)
    stage(Bbase, sB + 1 * 16384, 0, 1);   // B1(0)
    stage(Abase, sA + 2 * 16384, 1, 0);   // A0(1)
    stage(Bbase, sB + 2 * 16384, 1, 0);   // B0(1)

#define QK_PHASE(RH, KH, DO_STAGE, STAGE_EXPR, ENDBAR)                        \
  {                                                                           \
    const f16x8* pAh = (const f16x8*)(sA + (bufc * 2 + (KH)) * 16384);        \
    const f16x8* pBh = (const f16x8*)(sB + (bufc * 2 + (KH)) * 16384);        \
    f16x8 af[4], bf[4];                                                       \
    _Pragma("unroll")                                                         \
    for (int i = 0; i < 4; ++i)                                               \
      af[i] = pAh[(wm * 128 + (RH) * 64 + i * 16 + l16) * 4 + (quad ^ swz)];  \
    _Pragma("unroll")                                                         \
    for (int j = 0; j < 4; ++j)                                               \
      bf[j] = pBh[(wn * 64 + j * 16 + l16) * 4 + (quad ^ swz)];               \
    if (DO_STAGE) { STAGE_EXPR; }                                             \
    __builtin_amdgcn_s_barrier();                                             \
    asm volatile("s_waitcnt lgkmcnt(0)" ::: "memory");                        \
    __builtin_amdgcn_s_setprio(1);                                            \
    _Pragma("unroll")                                                         \
    for (int j = 0; j < 4; ++j)                                               \
      _Pragma("unroll")                                                       \
      for (int i = 0; i < 4; ++i)                                             \
        acc[(RH) * 4 + i][j] = __builtin_amdgcn_mfma_f32_16x16x32_f16(        \
            af[i], bf[j], acc[(RH) * 4 + i][j], 0, 0, 0);                     \
    __builtin_amdgcn_s_setprio(0);                                            \
    if (ENDBAR) __builtin_amdgcn_s_barrier();                                 \
  }

#define QK_TILE(T, S01, S23, LAST)                                            \
  {                                                                           \
    const int bufc = (T) & 1, bufn = bufc ^ 1;                                \
    if (LAST) asm volatile("s_waitcnt vmcnt(0)" ::: "memory");                \
    else      asm volatile("s_waitcnt vmcnt(4)" ::: "memory");                \
    __builtin_amdgcn_s_barrier();                                             \
    __builtin_amdgcn_sched_barrier(0);                                        \
    QK_PHASE(0, 0, S01, stage(Abase, sA + (bufn * 2 + 1) * 16384, (T) + 1, 1), 1) \
    QK_PHASE(1, 0, S01, stage(Bbase, sB + (bufn * 2 + 1) * 16384, (T) + 1, 1), 1) \
    QK_PHASE(0, 1, S23, stage(Abase, sA + (bufc * 2 + 0) * 16384, (T) + 2, 0), 1) \
    QK_PHASE(1, 1, S23, stage(Bbase, sB + (bufc * 2 + 0) * 16384, (T) + 2, 0), 0) \
  }

    for (int t = 0; t < 14; ++t) QK_TILE(t, 1, 1, 0)
    QK_TILE(14, 1, 0, 0)
    QK_TILE(15, 0, 0, 1)

#undef QK_TILE
#undef QK_PHASE

    // ---- epilogue: exp2 -> E fp16 + row-sum atomics ----
    #pragma unroll
    for (int i = 0; i < 8; ++i) {
        const int r0 = row0 + wm * 128 + i * 16 + quad * 4;
        float rp[4] = {0.f, 0.f, 0.f, 0.f};
        #pragma unroll
        for (int j = 0; j < 4; ++j) {
            const int cl = col0 + wn * 64 + j * 16 + l16;
            #pragma unroll
            for (int reg = 0; reg < 4; ++reg) {
                const float v = exp2f(alpha * acc[i][j][reg] - 5.770780163555856f);
                const _Float16 vh = (_Float16)v;
                E[(size_t)(r0 + reg) * SEQ + cl] = vh;
                rp[reg] += (float)vh;
            }
        }
        #pragma unroll
        for (int off = 1; off < 16; off <<= 1)
            #pragma unroll
            for (int reg = 0; reg < 4; ++reg)
                rp[reg] += __shfl_xor(rp[reg], off, 64);
        if (l16 == 0)
            #pragma unroll
            for (int reg = 0; reg < 4; ++reg)
                atomicAdd(&Lsum[r0 + reg], rp[reg]);
    }
}

// ===========================================================================
// PV kernel: 128x256 tile, 256 thr = 4 waves (2x2), wave tile 64x128.
// ~180 regs -> 2 blocks/CU (barrier-drain overlap). grid = 512 linear blocks.
// XCD swizzle: the 4 col-tile blocks sharing one E row-strip land on ONE XCD
// with adjacent slots -> shared A-tile K-loop front is an L2 hit (E re-reads
// stop going to HBM). A=E[b] (lda 4096), B=Vt[b] (ldb 4096).
// Cf[r*1024+c] = acc / Lsum[row].
// ===========================================================================
__global__ __launch_bounds__(256, 2)
void gemm_pv_kernel(const _Float16* __restrict__ A,
                    const _Float16* __restrict__ B,
                    float* __restrict__ Cf,
                    const float* __restrict__ Lsum) {
    __shared__ __align__(16) char smem[24576];
    char* sA = smem;            //  8 KB: 128 rows x 32 f16
    char* sB = smem + 8192;     // 16 KB: 256 rows x 32 f16

    const int tid  = threadIdx.x;
    const int lane = tid & 63;
    const int w    = tid >> 6;
    const int wm   = w & 1;           // 64-row half
    const int wn   = w >> 1;          // 128-col half
    const int quad = lane >> 4;
    const int l16  = lane & 15;
    const int swz  = (l16 >> 1) & 3;

    // swizzled decomposition: n%8 = XCD; c fastest within XCD slot group
    const int n    = blockIdx.x;          // 0..511
    const int xcd  = n & 7;
    const int slot = n >> 3;              // 0..63
    const int c    = slot & 3;            // col tile 0..3
    const int rg   = xcd + 8 * (slot >> 2);  // 0..127
    const int r    = rg & 31;             // row tile within batch
    const int bz   = rg >> 5;             // batch

    const int row0 = r * 128;
    const int col0 = c * 256;

    A    += (size_t)bz * SEQ * SEQ;
    B    += (size_t)bz * HIDDEN * SEQ;
    Cf   += (size_t)bz * SEQ * HIDDEN;
    Lsum += (size_t)bz * SEQ;

    floatx4 acc[4][8];
    #pragma unroll
    for (int i = 0; i < 4; ++i)
        #pragma unroll
        for (int j = 0; j < 8; ++j) acc[i][j] = (floatx4){0.f, 0.f, 0.f, 0.f};

    const f16x8* pA = (const f16x8*)sA;
    const f16x8* pB = (const f16x8*)sB;

    for (int k0 = 0; k0 < SEQ; k0 += 32) {
        // A: 512 chunks (2/thread); B: 1024 chunks (4/thread)
        #pragma unroll
        for (int it = 0; it < 2; ++it) {
            const int nc = tid + it * 256;
            const int sr = nc >> 2;
            const int sc = (nc & 3) ^ ((sr >> 1) & 3);
            gld16(A + (size_t)(row0 + sr) * SEQ + k0 + sc * 8, sA + nc * 16);
        }
        #pragma unroll
        for (int it = 0; it < 4; ++it) {
            const int nc = tid + it * 256;
            const int sr = nc >> 2;
            const int sc = (nc & 3) ^ ((sr >> 1) & 3);
            gld16(B + (size_t)(col0 + sr) * SEQ + k0 + sc * 8, sB + nc * 16);
        }
        __syncthreads();

        f16x8 af[4];
        #pragma unroll
        for (int i = 0; i < 4; ++i) {
            const int rr = wm * 64 + i * 16 + l16;
            af[i] = pA[rr * 4 + (quad ^ swz)];
        }
        #pragma unroll
        for (int j = 0; j < 8; ++j) {
            const int cc = wn * 128 + j * 16 + l16;
            const f16x8 bf = pB[cc * 4 + (quad ^ swz)];
            #pragma unroll
            for (int i = 0; i < 4; ++i)
                acc[i][j] = __builtin_amdgcn_mfma_f32_16x16x32_f16(af[i], bf, acc[i][j], 0, 0, 0);
        }
        __syncthreads();
    }

    #pragma unroll
    for (int i = 0; i < 4; ++i) {
        const int r0 = row0 + wm * 64 + i * 16 + quad * 4;
        float linv[4];
        #pragma unroll
        for (int reg = 0; reg < 4; ++reg) linv[reg] = 1.0f / Lsum[r0 + reg];
        #pragma unroll
        for (int j = 0; j < 8; ++j) {
            const int cl = col0 + wn * 128 + j * 16 + l16;
            #pragma unroll
            for (int reg = 0; reg < 4; ++reg)
                Cf[(size_t)(r0 + reg) * HIDDEN + cl] = acc[i][j][reg] * linv[reg];
        }
    }
}

// ---------------------------------------------------------------------------
// fp32 -> fp16 casts
// ---------------------------------------------------------------------------
__global__ __launch_bounds__(256)
void cast_x_kernel(const float* __restrict__ in, _Float16* __restrict__ out) {
    const int i = blockIdx.x * 256 + threadIdx.x;
    const float4 x = ((const float4*)in)[i];
    _Float16 h[4] = {(_Float16)x.x, (_Float16)x.y, (_Float16)x.z, (_Float16)x.w};
    ((uint2*)out)[i] = *(const uint2*)h;
}

__global__ __launch_bounds__(256)
void cast_w_kernel(const float* __restrict__ w0, const float* __restrict__ w1,
                   const float* __restrict__ w2,
                   _Float16* __restrict__ o0, _Float16* __restrict__ o1,
                   _Float16* __restrict__ o2) {
    const float* in = (blockIdx.z == 0) ? w0 : (blockIdx.z == 1) ? w1 : w2;
    _Float16* out   = (blockIdx.z == 0) ? o0 : (blockIdx.z == 1) ? o1 : o2;
    const int i = blockIdx.x * 256 + threadIdx.x;
    const float4 x = ((const float4*)in)[i];
    _Float16 h[4] = {(_Float16)x.x, (_Float16)x.y, (_Float16)x.z, (_Float16)x.w};
    ((uint2*)out)[i] = *(const uint2*)h;
}

// ---------------------------------------------------------------------------
// ws layout (bytes), total ~235 MB:
//   [0, 134.2M) : E fp16 [B][S][S]  (head aliases Xh + W casts, dead by then)
//   then        : Qh 33.5M | Kh 33.5M | Vt [B][H][S] 33.5M | Lsum 64K
// ---------------------------------------------------------------------------
extern "C" void kernel_launch(void* const* d_in, const int* in_sizes, int n_in,
                              void* d_out, int out_size, void* d_ws, size_t ws_size,
                              hipStream_t stream) {
    const float* X  = (const float*)d_in[0];
    const float* Wq = (const float*)d_in[1];
    const float* bq = (const float*)d_in[2];
    const float* Wk = (const float*)d_in[3];
    const float* bk = (const float*)d_in[4];
    const float* Wv = (const float*)d_in[5];
    const float* bv = (const float*)d_in[6];
    float* out = (float*)d_out;

    char* ws = (char*)d_ws;
    const size_t EB = (size_t)BATCH * SEQ * SEQ * 2;     // 134,217,728
    const size_t XB = (size_t)BATCH * SEQ * HIDDEN * 2;  // 33,554,432
    const size_t WB = (size_t)HIDDEN * HIDDEN * 2;       // 2,097,152

    _Float16* E   = (_Float16*)ws;
    _Float16* Xh  = (_Float16*)ws;                       // aliases E head
    _Float16* Wqh = (_Float16*)(ws + XB);
    _Float16* Wkh = (_Float16*)(ws + XB + WB);
    _Float16* Wvh = (_Float16*)(ws + XB + 2 * WB);
    _Float16* Qh  = (_Float16*)(ws + EB);
    _Float16* Kh  = (_Float16*)(ws + EB + XB);
    _Float16* Vt  = (_Float16*)(ws + EB + 2 * XB);       // [B][H][S]
    float*    Lsum= (float*)   (ws + EB + 3 * XB);       // [B][S]

    // 1. casts
    cast_x_kernel<<<dim3(16384), dim3(256), 0, stream>>>(X, Xh);
    cast_w_kernel<<<dim3(1024, 1, 3), dim3(256), 0, stream>>>(
        Wq, Wk, Wv, Wqh, Wkh, Wvh);

    hipMemsetAsync(Lsum, 0, (size_t)BATCH * SEQ * sizeof(float), stream);

    // 2. fused QKV projection: [16384,1024] x [3072,1024]^T, 128^2 tiles
    gemm128_kernel<5><<<dim3(24, 128, 1), dim3(256), 0, stream>>>(
        Xh, Wqh, Wkh, Wvh, bq, bk, bv, 1.0f,
        nullptr, Qh, Kh, Vt, nullptr,
        HIDDEN, HIDDEN, HIDDEN);

    // 3. QK^T -> exp -> E (fp16) + row sums: 256^2-tile 8-phase schedule
    const float alpha2 = (1.0f / 32.0f) * 1.4426950408889634f;  // /sqrt(H)*log2e
    qk8_kernel<<<dim3(256, 4), dim3(512), 0, stream>>>(Qh, Kh, E, Lsum, alpha2);

    // 4. PV with 1/Lsum scaling, 128x256 tiles + XCD swizzle
    gemm_pv_kernel<<<dim3(512), dim3(256), 0, stream>>>(E, Vt, out, Lsum);
}